// Round 4
// baseline (51.169 us; speedup 1.0000x reference)
//
#include <hip/hip_runtime.h>
#include <hip/hip_bf16.h>

#define MAXO 25
#define WCHUNK 512    // timesteps per wave (8 rounds of 64)
#define BCHUNK 2048   // timesteps per block (4 waves)

typedef float f32x4 __attribute__((ext_vector_type(4)));   // clang vector: NT-store ok

// ---------------------------------------------------------------------------
// Pass 1: per-BLOCK count of ones (2048 timesteps per block).
// ---------------------------------------------------------------------------
__global__ __launch_bounds__(256) void pda_sums(
    const int* __restrict__ seq, unsigned* __restrict__ blk_sums, int T)
{
    __shared__ unsigned ws[4];
    const int lane = threadIdx.x & 63;
    const int wid  = threadIdx.x >> 6;

    const long t0 = (long)blockIdx.x * BCHUNK + (long)wid * WCHUNK + (long)lane * 8;
    unsigned s = 0;
    if (t0 + 8 <= (long)T) {
        const int4* p = (const int4*)(seq + t0);   // 32B-aligned
        int4 a = p[0], b = p[1];
        s = (unsigned)(a.x + a.y + a.z + a.w + b.x + b.y + b.z + b.w);
    } else {
        for (int k = 0; k < 8; ++k) {
            long t = t0 + k;
            if (t < (long)T) s += (unsigned)seq[t];
        }
    }
    #pragma unroll
    for (int off = 32; off; off >>= 1) s += __shfl_down(s, off, 64);
    if (lane == 0) ws[wid] = s;
    __syncthreads();
    if (threadIdx.x == 0)
        blk_sums[blockIdx.x] = ws[0] + ws[1] + ws[2] + ws[3];
}

// ---------------------------------------------------------------------------
// Pass 2 (main): each block redundantly reduces preceding block sums, then
// computes counter -> soft_clamp -> 25-way softmax; stages in PER-WAVE LDS
// (no barriers in the round loop — intra-wave dependencies only); coalesced
// nontemporal float4 stores.
// ---------------------------------------------------------------------------
__global__ __launch_bounds__(256) void pda_main(
    const int* __restrict__ seq, const unsigned* __restrict__ blk_sums,
    const float* __restrict__ delta, const float* __restrict__ scale_p,
    float* __restrict__ out, int T)
{
    __shared__ __align__(16) float stage[4][64 * MAXO];  // 25.6 KB, per-wave slices
    __shared__ unsigned wsum[4];
    __shared__ unsigned bpart[4];

    const int lane = threadIdx.x & 63;
    const int wid  = threadIdx.x >> 6;
    const int bid  = blockIdx.x;
    const long wbase = (long)bid * BCHUNK + (long)wid * WCHUNK;

    const float d0 = delta[0];
    const float dd = delta[1] - d0;
    const float scale = scale_p[0];
    const float inv_denom = 1.0f / (24.0f + 1e-6f);

    // --- load my wave's 512 bits; keep ballot masks (wave-uniform scalars) ---
    unsigned long long m[8];
    unsigned mycnt = 0;
    #pragma unroll
    for (int r = 0; r < 8; ++r) {
        long t = wbase + (long)r * 64 + lane;
        int b = (t < (long)T) ? seq[t] : 0;
        m[r] = __ballot(b != 0);
        mycnt += (unsigned)__popcll(m[r]);     // uniform across the wave
    }
    if (lane == 0) wsum[wid] = mycnt;

    // --- redundant reduction of preceding block sums (3.9 KB, L2-hot) ---
    unsigned p = 0;
    for (int i = (int)threadIdx.x; i < bid; i += 256) p += blk_sums[i];
    #pragma unroll
    for (int off = 32; off; off >>= 1) p += __shfl_down(p, off, 64);
    if (lane == 0) bpart[wid] = p;
    __syncthreads();   // the ONLY block-wide barrier (wsum/bpart publication)

    unsigned run = bpart[0] + bpart[1] + bpart[2] + bpart[3];
    for (int w = 0; w < wid; ++w) run += wsum[w];

    const unsigned long long le_mask = (lane == 63) ? ~0ULL : ((2ULL << lane) - 1ULL);

    for (int r = 0; r < 8; ++r) {
        const long rbase = wbase + (long)r * 64;
        const long t = rbase + lane;

        unsigned ones_incl = run + (unsigned)__popcll(m[r] & le_mask);

        // counter = (t+1)*d0 + ones*(d1-d0)  (exact for this data)
        float c   = (float)(t + 1) * d0 + (float)ones_incl * dd;
        float z   = 10.0f * (c * inv_denom - 0.5f);
        float sig = 1.0f / (1.0f + __expf(-z));
        float cs  = sig * 24.0f;

        float w[MAXO];
        float sum = 0.0f;
        #pragma unroll
        for (int j = 0; j < MAXO; ++j) {
            float dist = fabsf((float)j - cs);
            w[j] = __expf(-scale * dist);
            sum += w[j];
        }
        float inv = 1.0f / sum;

        // Per-wave private LDS slice: no block barrier needed. Compiler's
        // waitcnts order ds_write -> ds_read -> global_store within the wave.
        #pragma unroll
        for (int j = 0; j < MAXO; ++j)
            stage[wid][lane * MAXO + j] = w[j] * inv;   // stride 25: conflict-free

        // valid timestep count this round (uniform per wave)
        long rem = (long)T - rbase;
        int V = (rem >= 64) ? 64 : (rem < 0 ? 0 : (int)rem);

        if (V == 64) {
            f32x4* o4 = (f32x4*)(out + rbase * MAXO);              // 6400B-aligned
            const f32x4* s4 = (const f32x4*)&stage[wid][0];
            #pragma unroll
            for (int s = 0; s < 6; ++s)
                __builtin_nontemporal_store(s4[s * 64 + lane], &o4[s * 64 + lane]);
            if (lane < 16)
                __builtin_nontemporal_store(s4[384 + lane], &o4[384 + lane]);
        } else if (V > 0) {
            int F = V * MAXO;
            for (int f = lane; f < F; f += 64)
                out[rbase * MAXO + f] = stage[wid][f];
        }

        run += (unsigned)__popcll(m[r]);
    }
}

// ---------------------------------------------------------------------------
extern "C" void kernel_launch(void* const* d_in, const int* in_sizes, int n_in,
                              void* d_out, int out_size, void* d_ws, size_t ws_size,
                              hipStream_t stream)
{
    const float* delta   = (const float*)d_in[0];
    const float* scale_p = (const float*)d_in[1];
    const int*   seq     = (const int*)d_in[2];
    const int T = in_sizes[2];
    const int nblocks = (T + BCHUNK - 1) / BCHUNK;

    unsigned* blk_sums = (unsigned*)d_ws;   // nblocks * 4 bytes

    pda_sums<<<nblocks, 256, 0, stream>>>(seq, blk_sums, T);
    pda_main<<<nblocks, 256, 0, stream>>>(seq, blk_sums, delta, scale_p,
                                          (float*)d_out, T);
}

// Round 5
// 42.949 us; speedup vs baseline: 1.1914x; 1.1914x over previous
//
#include <hip/hip_runtime.h>
#include <hip/hip_bf16.h>

#define MAXO 25
#define WCHUNK 512    // timesteps per wave (8 rounds of 64)
#define BCHUNK 2048   // timesteps per block (4 waves)

// ---------------------------------------------------------------------------
// Pass 1: per-BLOCK count of ones (2048 timesteps per block).
// ---------------------------------------------------------------------------
__global__ __launch_bounds__(256) void pda_sums(
    const int* __restrict__ seq, unsigned* __restrict__ blk_sums, int T)
{
    __shared__ unsigned ws[4];
    const int lane = threadIdx.x & 63;
    const int wid  = threadIdx.x >> 6;

    const long t0 = (long)blockIdx.x * BCHUNK + (long)wid * WCHUNK + (long)lane * 8;
    unsigned s = 0;
    if (t0 + 8 <= (long)T) {
        const int4* p = (const int4*)(seq + t0);   // 32B-aligned
        int4 a = p[0], b = p[1];
        s = (unsigned)(a.x + a.y + a.z + a.w + b.x + b.y + b.z + b.w);
    } else {
        for (int k = 0; k < 8; ++k) {
            long t = t0 + k;
            if (t < (long)T) s += (unsigned)seq[t];
        }
    }
    #pragma unroll
    for (int off = 32; off; off >>= 1) s += __shfl_down(s, off, 64);
    if (lane == 0) ws[wid] = s;
    __syncthreads();
    if (threadIdx.x == 0)
        blk_sums[blockIdx.x] = ws[0] + ws[1] + ws[2] + ws[3];
}

// ---------------------------------------------------------------------------
// Pass 2 (main): each block redundantly reduces preceding block sums, then
// computes counter -> soft_clamp -> 25-way softmax; stages in PER-WAVE LDS
// (no barriers in the round loop); coalesced regular float4 stores.
// ---------------------------------------------------------------------------
__global__ __launch_bounds__(256) void pda_main(
    const int* __restrict__ seq, const unsigned* __restrict__ blk_sums,
    const float* __restrict__ delta, const float* __restrict__ scale_p,
    float* __restrict__ out, int T)
{
    __shared__ __align__(16) float stage[4][64 * MAXO];  // 25.6 KB, per-wave slices
    __shared__ unsigned wsum[4];
    __shared__ unsigned bpart[4];

    const int lane = threadIdx.x & 63;
    const int wid  = threadIdx.x >> 6;
    const int bid  = blockIdx.x;
    const long wbase = (long)bid * BCHUNK + (long)wid * WCHUNK;

    const float d0 = delta[0];
    const float dd = delta[1] - d0;
    const float scale = scale_p[0];
    const float inv_denom = 1.0f / (24.0f + 1e-6f);

    // --- load my wave's 512 bits; keep ballot masks (wave-uniform scalars) ---
    unsigned long long m[8];
    unsigned mycnt = 0;
    #pragma unroll
    for (int r = 0; r < 8; ++r) {
        long t = wbase + (long)r * 64 + lane;
        int b = (t < (long)T) ? seq[t] : 0;
        m[r] = __ballot(b != 0);
        mycnt += (unsigned)__popcll(m[r]);     // uniform across the wave
    }
    if (lane == 0) wsum[wid] = mycnt;

    // --- redundant reduction of preceding block sums (3.9 KB, L2-hot) ---
    unsigned p = 0;
    for (int i = (int)threadIdx.x; i < bid; i += 256) p += blk_sums[i];
    #pragma unroll
    for (int off = 32; off; off >>= 1) p += __shfl_down(p, off, 64);
    if (lane == 0) bpart[wid] = p;
    __syncthreads();   // the ONLY block-wide barrier (wsum/bpart publication)

    unsigned run = bpart[0] + bpart[1] + bpart[2] + bpart[3];
    for (int w = 0; w < wid; ++w) run += wsum[w];

    const unsigned long long le_mask = (lane == 63) ? ~0ULL : ((2ULL << lane) - 1ULL);

    for (int r = 0; r < 8; ++r) {
        const long rbase = wbase + (long)r * 64;
        const long t = rbase + lane;

        unsigned ones_incl = run + (unsigned)__popcll(m[r] & le_mask);

        // counter = (t+1)*d0 + ones*(d1-d0)  (exact for this data)
        float c   = (float)(t + 1) * d0 + (float)ones_incl * dd;
        float z   = 10.0f * (c * inv_denom - 0.5f);
        float sig = 1.0f / (1.0f + __expf(-z));
        float cs  = sig * 24.0f;

        float w[MAXO];
        float sum = 0.0f;
        #pragma unroll
        for (int j = 0; j < MAXO; ++j) {
            float dist = fabsf((float)j - cs);
            w[j] = __expf(-scale * dist);
            sum += w[j];
        }
        float inv = 1.0f / sum;

        // Per-wave private LDS slice: no block barrier needed. Compiler's
        // waitcnts order ds_write -> ds_read -> global_store within the wave.
        #pragma unroll
        for (int j = 0; j < MAXO; ++j)
            stage[wid][lane * MAXO + j] = w[j] * inv;   // stride 25: conflict-free

        // valid timestep count this round (uniform per wave)
        long rem = (long)T - rbase;
        int V = (rem >= 64) ? 64 : (rem < 0 ? 0 : (int)rem);

        if (V == 64) {
            float4* o4 = (float4*)(out + rbase * MAXO);            // 6400B-aligned
            const float4* s4 = (const float4*)&stage[wid][0];
            #pragma unroll
            for (int s = 0; s < 6; ++s)
                o4[s * 64 + lane] = s4[s * 64 + lane];
            if (lane < 16) o4[384 + lane] = s4[384 + lane];
        } else if (V > 0) {
            int F = V * MAXO;
            for (int f = lane; f < F; f += 64)
                out[rbase * MAXO + f] = stage[wid][f];
        }

        run += (unsigned)__popcll(m[r]);
    }
}

// ---------------------------------------------------------------------------
extern "C" void kernel_launch(void* const* d_in, const int* in_sizes, int n_in,
                              void* d_out, int out_size, void* d_ws, size_t ws_size,
                              hipStream_t stream)
{
    const float* delta   = (const float*)d_in[0];
    const float* scale_p = (const float*)d_in[1];
    const int*   seq     = (const int*)d_in[2];
    const int T = in_sizes[2];
    const int nblocks = (T + BCHUNK - 1) / BCHUNK;

    unsigned* blk_sums = (unsigned*)d_ws;   // nblocks * 4 bytes

    pda_sums<<<nblocks, 256, 0, stream>>>(seq, blk_sums, T);
    pda_main<<<nblocks, 256, 0, stream>>>(seq, blk_sums, delta, scale_p,
                                          (float*)d_out, T);
}